// Round 14
// baseline (373.431 us; speedup 1.0000x reference)
//
#include <hip/hip_runtime.h>

// ---------------------------------------------------------------------------
// DCGRU cell on MI355X — double-hop kernel (hop1+hop2 fused per (b,s)).
// B=32, N=1024, C_IN=2, H=32, S=2, K=2, NUM_MAT=5, c_cat=34.
//
// ws (pathA): [Aq 64MB][H1 15MB][H2 15MB][Xq1 7.5MB][Xq2 7.5MB][ubuf 4MB]
// Aq:  i8 supports, scale sA=(2/1024)/127, [mat][row][k] row-major, mat=b*2+s.
// Xq*: i8 slot-0 feature image [b][48 ch][1024 n], scale 127/8.
// H:   bf16 gate inputs, per b: 5 slots x 3 ct x [16 ch][1024 n].
// Output: d_out = (outputs, outputs), each 1,048,576 fp32.
//
// dhop: one block per (b,s) (64 blocks x 512 thr, 144 KB LDS). X panel and
// Z (=A.X, i8) LDS-resident; A streamed twice (pass1: X->Z+H slots 1|3;
// pass2: Z->H slots 2|4, A re-read L2-hot) through a 3-buffer 128-step
// counted-vmcnt ring (vmcnt(2), lgkmcnt(0), never drains mid-pass).
// Chunk-permutation convention (proven r12/r13): slot s holds source chunk
// s^(row&7); COMPUTE reads chunk j at slot j^(row&7); same for ch images.
// ---------------------------------------------------------------------------

#define NN   1024
#define HB   245760
#define SUBT 16384
#define OUTCOPY 1048576
#define XSL  49152      // 48*1024 bytes per (b, slot)
#define ABUF 16384      // one A ring buffer (128 rows x 128 k i8)

typedef float  f32x4  __attribute__((ext_vector_type(4)));
typedef int    i32x4  __attribute__((ext_vector_type(4)));
typedef short  s16x4  __attribute__((ext_vector_type(4)));
typedef __bf16 bf16x8 __attribute__((ext_vector_type(8)));
typedef char   s8x4   __attribute__((ext_vector_type(4)));
typedef char   s8x8   __attribute__((ext_vector_type(8)));
typedef unsigned int u32x4 __attribute__((ext_vector_type(4)));

#define GAS __attribute__((address_space(1)))
#define LAS __attribute__((address_space(3)))

__device__ __forceinline__ unsigned short f32_bf16(float f) {
  unsigned int u = __float_as_uint(f);
  u += 0x7FFFu + ((u >> 16) & 1u);        // RNE
  return (unsigned short)(u >> 16);
}
__device__ __forceinline__ float bf16_f32(unsigned short h) {
  return __uint_as_float(((unsigned int)h) << 16);
}
__device__ __forceinline__ void gload_lds16(const void* g, void* l) {
  __builtin_amdgcn_global_load_lds((const GAS void*)g, (LAS void*)l, 16, 0, 0);
}
__device__ __forceinline__ signed char q8(float v, float s) {
  return (signed char)fminf(fmaxf(rintf(v * s), -127.f), 127.f);
}

// ---------------------------------------------------------------------------
// cvt_i8: supports fp32 -> Aq i8 (q = rint(A*65024), A in [0, 2/1024])
// ---------------------------------------------------------------------------
__global__ __launch_bounds__(256)
void cvt_i8(const float* __restrict__ src, signed char* __restrict__ dst, int n8) {
  int i = blockIdx.x * 256 + threadIdx.x;
  int stride = gridDim.x * 256;
  for (; i < n8; i += stride) {
    f32x4 a = ((const f32x4*)src)[i * 2];
    f32x4 b = ((const f32x4*)src)[i * 2 + 1];
    s8x8 o;
#pragma unroll
    for (int j = 0; j < 4; ++j) o[j]     = (char)fminf(fmaxf(rintf(a[j] * 65024.f), 0.f), 127.f);
#pragma unroll
    for (int j = 0; j < 4; ++j) o[4 + j] = (char)fminf(fmaxf(rintf(b[j] * 65024.f), 0.f), 127.f);
    *(s8x8*)(dst + (size_t)i * 8) = o;
  }
}

// ---------------------------------------------------------------------------
// pack x1 = [inputs, states]: bf16 H1 slot0 + i8 Xq1 slot0 (scale 127/8)
// ---------------------------------------------------------------------------
__global__ __launch_bounds__(256)
void pack_x1(const float* __restrict__ inputs, const float* __restrict__ states,
             unsigned short* __restrict__ H1, signed char* __restrict__ Xq1) {
  int gid = blockIdx.x * 256 + threadIdx.x;   // 0..32767
  int b = gid >> 10, n = gid & 1023;
  unsigned short* xb = H1 + (size_t)b * HB;
  signed char*    xq = Xq1 ? Xq1 + (size_t)b * 5 * XSL : nullptr;
  float i0 = inputs[gid * 2 + 0], i1 = inputs[gid * 2 + 1];
  xb[0 * NN + n] = f32_bf16(i0);
  xb[1 * NN + n] = f32_bf16(i1);
  if (xq) { xq[0 * NN + n] = q8(i0, 15.875f); xq[1 * NN + n] = q8(i1, 15.875f); }
#pragma unroll
  for (int o = 0; o < 32; ++o) {
    int ch = 2 + o;
    float sv = states[gid * 32 + o];
    xb[(ch >> 4) * SUBT + (ch & 15) * NN + n] = f32_bf16(sv);
    if (xq) xq[ch * NN + n] = q8(sv, 15.875f);
  }
#pragma unroll
  for (int ch = 34; ch < 48; ++ch) {
    xb[2 * SUBT + (ch & 15) * NN + n] = 0;
    if (xq) xq[ch * NN + n] = 0;
  }
}

// ---------------------------------------------------------------------------
// dhop: hop1 + hop2 for one (b,s). Outputs H slots 1|3 (hop1), 2|4 (hop2).
// ---------------------------------------------------------------------------
__global__ __launch_bounds__(512, 1)
void dhop(const signed char* __restrict__ Aq,
          const signed char* __restrict__ Xq,
          unsigned short* __restrict__ H,
          float dq1, float dq2) {
  __shared__ u32x4 ldsv[9216];      // 144 KB: [0,48K) X, [48K,96K) Z, [96K,144K) A ring
  char* lds = (char*)ldsv;
  char* Xb  = lds;
  char* Zb  = lds + 49152;
  char* Ar  = lds + 98304;

  const int tid  = threadIdx.x;
  const int wave = tid >> 6, lane = tid & 63;
  const int l15  = lane & 15,  l4  = lane >> 4;
  const int mat  = blockIdx.x;            // 0..63
  const int b    = mat >> 1, s = mat & 1;

  const signed char* Ab  = Aq + ((size_t)mat << 20);
  const signed char* Xqc = Xq + (size_t)b * 5 * XSL;   // slot 0
  unsigned short*    Y1  = H + (size_t)b * HB + (size_t)(s ? 3 : 1) * 3 * SUBT;
  unsigned short*    Y2  = H + (size_t)b * HB + (size_t)(s ? 4 : 2) * 3 * SUBT;

  // ---- stage X panel (48 KB, 3072 chunks, 6/thread), per-ktile blocks ----
#pragma unroll
  for (int i = 0; i < 6; ++i) {
    int q  = i * 512 + tid;               // 0..3071
    int kt = q / 384, r = q - kt * 384;
    int ch = r >> 3, c8 = r & 7;
    gload_lds16(Xqc + ch * 1024 + kt * 128 + ((c8 ^ (ch & 7)) << 4),
                Xb + q * 16);
  }
  __syncthreads();                        // X ready (drains vmcnt)

  // ---- A-tile issue: step st -> tile t=st&63 (mb=t>>3, kt=t&7) ----
  auto ISSUE = [&](int st, char* base) {
    const int t = st & 63;
    const int mb = t >> 3, kt = t & 7;
#pragma unroll
    for (int i = 0; i < 2; ++i) {
      int q = i * 512 + tid;              // 0..1023
      int r = q >> 3, c8 = q & 7;
      gload_lds16(Ab + (size_t)(mb * 128 + r) * 1024 + kt * 128 + ((c8 ^ (r & 7)) << 4),
                  base + q * 16);
    }
  };

  i32x4 acc[3];
#pragma unroll
  for (int nt = 0; nt < 3; ++nt)
#pragma unroll
    for (int e = 0; e < 4; ++e) acc[nt][e] = 0;

  const int row  = wave * 16 + l15;       // A row within 128-row strip
  const int swk  = l15 & 7;               // row&7 == ch&7 == l15&7
  const int jhi  = l4 >> 1;
  const int sub8 = (l4 & 1) << 3;

  auto COMPUTE = [&](const char* bufA, const char* xzb, int kt) {
    const char* pan = xzb + kt * 6144;
#pragma unroll
    for (int kb = 0; kb < 4; ++kb) {
      const int j  = kb * 2 + jhi;
      const int co = ((j ^ swk) << 4) + sub8;
      long afr = *(const long*)(bufA + row * 128 + co);
#pragma unroll
      for (int nt = 0; nt < 3; ++nt) {
        int ch = nt * 16 + l15;
        long xfr = *(const long*)(pan + ch * 128 + co);
        acc[nt] = __builtin_amdgcn_mfma_i32_16x16x32_i8(afr, xfr, acc[nt], 0, 0, 0);
      }
    }
  };

  // epilogue after finishing mb (8 ktiles): write H bf16 (+Z i8 in pass 1)
  auto EPI = [&](int pass, int mb) {
    const float dq = pass ? dq2 : dq1;
    unsigned short* Y = pass ? Y2 : Y1;
    const int row0 = mb * 128 + wave * 16 + (l4 << 2);
#pragma unroll
    for (int nt = 0; nt < 3; ++nt) {
      int ch = nt * 16 + l15;
      f32x4 v;
#pragma unroll
      for (int e = 0; e < 4; ++e) v[e] = (float)acc[nt][e] * dq;
      s16x4 o;
      o.x = (short)f32_bf16(v[0]);
      o.y = (short)f32_bf16(v[1]);
      o.z = (short)f32_bf16(v[2]);
      o.w = (short)f32_bf16(v[3]);
      *(s16x4*)(Y + (size_t)ch * NN + row0) = o;
      if (!pass) {
        s8x4 qv;
#pragma unroll
        for (int e = 0; e < 4; ++e) qv[e] = q8(v[e], 254.f);
        // Z image: chunk index = wave, byte = l4*4+e, block = mb
        *(s8x4*)(Zb + mb * 6144 + ch * 128 + ((wave ^ (ch & 7)) << 4) + (l4 << 2)) = qv;
      }
#pragma unroll
      for (int e = 0; e < 4; ++e) acc[nt][e] = 0;
    }
  };

#define WB(N) do {                                                        \
    asm volatile("s_waitcnt vmcnt(" #N ") lgkmcnt(0)" ::: "memory");      \
    __builtin_amdgcn_s_barrier();                                         \
    __builtin_amdgcn_sched_barrier(0);                                    \
  } while (0)

  char* bA = Ar;
  char* bB = Ar + ABUF;
  char* bC = Ar + 2 * ABUF;

  ISSUE(0, bA);
  ISSUE(1, bB);

#pragma unroll 1
  for (int st = 0; st < 126; ++st) {
    WB(2);                                 // tile st ready everywhere
    ISSUE(st + 2, bC);                     // overwrite tile st-1's buffer
    const int pass = st >> 6, t = st & 63;
    COMPUTE(bA, pass ? Zb : Xb, t & 7);
    if ((t & 7) == 7) EPI(pass, t >> 3);
    char* tp = bA; bA = bB; bB = bC; bC = tp;
  }
  WB(2);                                   // st=126
  COMPUTE(bA, Zb, 6);
  { char* tp = bA; bA = bB; bB = bC; bC = tp; }
  WB(0);                                   // st=127
  COMPUTE(bA, Zb, 7);
  EPI(1, 7);

#undef WB
}

// ---------------------------------------------------------------------------
// gate_ru: r_u = sigmoid(h1 @ W_ru + b_ru); writes H2 slot0 (bf16) + Xq2
// slot0 (i8) + u.
// ---------------------------------------------------------------------------
__global__ __launch_bounds__(256)
void gate_ru_k(const unsigned short* __restrict__ H1,
               const float* __restrict__ W, const float* __restrict__ bias,
               const float* __restrict__ inputs, const float* __restrict__ states,
               unsigned short* __restrict__ H2, signed char* __restrict__ Xq2,
               float* __restrict__ ubuf) {
  int gid = blockIdx.x * 256 + threadIdx.x;
  int b = gid >> 10, n = gid & 1023;
  const unsigned short* hb = H1 + (size_t)b * HB;
  float acc[64];
#pragma unroll
  for (int o = 0; o < 64; ++o) acc[o] = bias[o];
  for (int j = 0; j < 5; ++j) {
    const unsigned short* sb = hb + j * 3 * SUBT;
    for (int c = 0; c < 34; ++c) {
      float xv = bf16_f32(sb[(c >> 4) * SUBT + (c & 15) * NN + n]);
      const float* wr = W + (j * 34 + c) * 64;
#pragma unroll
      for (int o = 0; o < 64; ++o) acc[o] = fmaf(xv, wr[o], acc[o]);
    }
  }
  unsigned short* xb = H2 + (size_t)b * HB;
  signed char*    xq = Xq2 ? Xq2 + (size_t)b * 5 * XSL : nullptr;
  float i0 = inputs[gid * 2 + 0], i1 = inputs[gid * 2 + 1];
  xb[0 * NN + n] = f32_bf16(i0);
  xb[1 * NN + n] = f32_bf16(i1);
  if (xq) { xq[0 * NN + n] = q8(i0, 15.875f); xq[1 * NN + n] = q8(i1, 15.875f); }
#pragma unroll
  for (int o = 0; o < 32; ++o) {
    float r = 1.f / (1.f + __expf(-acc[o]));
    float u = 1.f / (1.f + __expf(-acc[32 + o]));
    float sv = states[gid * 32 + o];
    int ch = 2 + o;
    float rs = r * sv;
    xb[(ch >> 4) * SUBT + (ch & 15) * NN + n] = f32_bf16(rs);
    if (xq) xq[ch * NN + n] = q8(rs, 15.875f);
    ubuf[((size_t)b * 32 + o) * NN + n] = u;
  }
#pragma unroll
  for (int ch = 34; ch < 48; ++ch) {
    xb[2 * SUBT + (ch & 15) * NN + n] = 0;
    if (xq) xq[ch * NN + n] = 0;
  }
}

// ---------------------------------------------------------------------------
// gate_c: c = tanh(h2 @ W_c + b_c); out = u*states + (1-u)*c (written twice)
// ---------------------------------------------------------------------------
__global__ __launch_bounds__(256)
void gate_c_k(const unsigned short* __restrict__ H2,
              const float* __restrict__ W, const float* __restrict__ bias,
              const float* __restrict__ states, const float* __restrict__ ubuf,
              float* __restrict__ out) {
  int gid = blockIdx.x * 256 + threadIdx.x;
  int b = gid >> 10, n = gid & 1023;
  const unsigned short* hb = H2 + (size_t)b * HB;
  float acc[32];
#pragma unroll
  for (int o = 0; o < 32; ++o) acc[o] = bias[o];
  for (int j = 0; j < 5; ++j) {
    const unsigned short* sb = hb + j * 3 * SUBT;
    for (int c = 0; c < 34; ++c) {
      float xv = bf16_f32(sb[(c >> 4) * SUBT + (c & 15) * NN + n]);
      const float* wr = W + (j * 34 + c) * 32;
#pragma unroll
      for (int o = 0; o < 32; ++o) acc[o] = fmaf(xv, wr[o], acc[o]);
    }
  }
  float res[32];
#pragma unroll
  for (int o = 0; o < 32; ++o) {
    float cc = tanhf(acc[o]);
    float u  = ubuf[((size_t)b * 32 + o) * NN + n];
    float sv = states[gid * 32 + o];
    res[o] = u * sv + (1.f - u) * cc;
  }
  float* o0 = out + (size_t)gid * 32;
#pragma unroll
  for (int q = 0; q < 8; ++q) {
    f32x4 v = { res[q * 4 + 0], res[q * 4 + 1], res[q * 4 + 2], res[q * 4 + 3] };
    *(f32x4*)(o0 + q * 4) = v;
    *(f32x4*)(o0 + OUTCOPY + q * 4) = v;
  }
}

// ---------------------------------------------------------------------------
// hop_slow fallback (fp32 A, bf16 MFMA, reg-staged) — proven round-2 version
// ---------------------------------------------------------------------------
__global__ __launch_bounds__(256)
void hop_slow(const float* __restrict__ Af32,
              const unsigned short* __restrict__ Hin,
              unsigned short* __restrict__ Hout,
              int si0, int si1, int so0, int so1) {
  __shared__ u32x4 lA4[1024];
  __shared__ u32x4 lX4[384];
  typedef short s16x8l __attribute__((ext_vector_type(8)));
  const int tid  = threadIdx.x;
  const int wave = tid >> 6, lane = tid & 63;
  const int l15  = lane & 15,  l4  = lane >> 4;
  const int mblk = blockIdx.x, b = blockIdx.y, s = blockIdx.z;
  const int slot_in  = s ? si1 : si0;
  const int slot_out = s ? so1 : so0;
  const unsigned short* Xb = Hin  + (size_t)b * HB + (size_t)slot_in  * 3 * SUBT;
  unsigned short*       Yb = Hout + (size_t)b * HB + (size_t)slot_out * 3 * SUBT;
  const size_t arow0 = ((size_t)(b * 2 + s) * NN + (size_t)mblk * 128) * NN;
  f32x4 acc[2][3];
#pragma unroll
  for (int mt = 0; mt < 2; ++mt)
#pragma unroll
    for (int nt = 0; nt < 3; ++nt)
#pragma unroll
      for (int e = 0; e < 4; ++e) acc[mt][nt][e] = 0.f;
  char* lAb = (char*)lA4;
  char* lXb = (char*)lX4;
  for (int kt = 0; kt < 16; ++kt) {
    const int kb0 = kt * 64;
    __syncthreads();
#pragma unroll
    for (int i = 0; i < 8; ++i) {
      int q = i * 256 + tid;
      int r = q >> 4, c = q & 15;
      float4 v = *(const float4*)(Af32 + arow0 + (size_t)r * NN + kb0 + c * 4);
      s16x4 o;
      o.x = (short)f32_bf16(v.x); o.y = (short)f32_bf16(v.y);
      o.z = (short)f32_bf16(v.z); o.w = (short)f32_bf16(v.w);
      *(s16x4*)(lAb + r * 128 + ((c * 8) ^ ((r & 7) << 4))) = o;
    }
    {
      int q = tid;
      int ct = q >> 7, rem = q & 127, ch = rem >> 3, c = rem & 7;
      const u32x4* src = (const u32x4*)(Xb + ct * SUBT + ch * NN + kb0 + c * 8);
      *(u32x4*)(lXb + ct * 2048 + ch * 128 + ((c ^ (ch & 7)) << 4)) = *src;
      if (tid < 128) {
        q = 256 + tid;
        ct = q >> 7; rem = q & 127; ch = rem >> 3; c = rem & 7;
        src = (const u32x4*)(Xb + ct * SUBT + ch * NN + kb0 + c * 8);
        *(u32x4*)(lXb + ct * 2048 + ch * 128 + ((c ^ (ch & 7)) << 4)) = *src;
      }
    }
    __syncthreads();
#pragma unroll
    for (int kb = 0; kb < 2; ++kb) {
      const int ko = kb * 64 + (l4 << 3);
      bf16x8 afr[2];
#pragma unroll
      for (int mt = 0; mt < 2; ++mt) {
        int row = wave * 32 + mt * 16 + l15;
        int sw  = (row & 7) << 4;
        s16x8l t;
        t.lo = *(const s16x4*)(lAb + row * 128 + (ko ^ sw));
        t.hi = *(const s16x4*)(lAb + row * 128 + ((ko + 32) ^ sw));
        afr[mt] = __builtin_bit_cast(bf16x8, t);
      }
#pragma unroll
      for (int nt = 0; nt < 3; ++nt) {
        const int swx = (l15 & 7) << 4;
        const char* bp = lXb + nt * 2048 + l15 * 128;
        s16x8l t;
        t.lo = *(const s16x4*)(bp + (ko ^ swx));
        t.hi = *(const s16x4*)(bp + ((ko + 32) ^ swx));
        bf16x8 bfr = __builtin_bit_cast(bf16x8, t);
#pragma unroll
        for (int mt = 0; mt < 2; ++mt)
          acc[mt][nt] = __builtin_amdgcn_mfma_f32_16x16x32_bf16(afr[mt], bfr, acc[mt][nt], 0, 0, 0);
      }
    }
  }
#pragma unroll
  for (int mt = 0; mt < 2; ++mt)
#pragma unroll
    for (int nt = 0; nt < 3; ++nt) {
      int ch   = nt * 16 + l15;
      int row0 = mblk * 128 + wave * 32 + mt * 16 + (l4 << 2);
      s16x4 o;
      o.x = (short)f32_bf16(acc[mt][nt][0]); o.y = (short)f32_bf16(acc[mt][nt][1]);
      o.z = (short)f32_bf16(acc[mt][nt][2]); o.w = (short)f32_bf16(acc[mt][nt][3]);
      *(s16x4*)(Yb + (size_t)ch * NN + row0) = o;
    }
}

// ---------------------------------------------------------------------------
extern "C" void kernel_launch(void* const* d_in, const int* in_sizes, int n_in,
                              void* d_out, int out_size, void* d_ws, size_t ws_size,
                              hipStream_t stream) {
  (void)in_sizes; (void)n_in; (void)out_size;
  const float* inputs   = (const float*)d_in[0];
  const float* supports = (const float*)d_in[1];
  const float* states   = (const float*)d_in[2];
  const float* W_ru     = (const float*)d_in[3];
  const float* b_ru     = (const float*)d_in[4];
  const float* W_c      = (const float*)d_in[5];
  const float* b_c      = (const float*)d_in[6];
  float* out = (float*)d_out;

  char* ws = (char*)d_ws;
  const size_t szA  = 67108864;    // i8 supports
  const size_t szH  = 15728640;
  const size_t szXq = 7864320;
  const size_t szU  = 4194304;
  const bool pathA = ws_size >= szA + 2 * szH + 2 * szXq + szU;

  const float sA  = 2.0f / (1024.f * 127.f);
  const float dq1 = sA * (8.0f / 127.f);    // pass 1 dequant (X scale 127/8)
  const float dq2 = sA * (0.5f / 127.f);    // pass 2 dequant (Z scale 127/0.5)

  dim3 sgrid(8, 32, 2), blk256(256);

  if (pathA) {
    signed char*    Aq  = (signed char*)ws;
    unsigned short* H1  = (unsigned short*)(ws + szA);
    unsigned short* H2  = (unsigned short*)(ws + szA + szH);
    signed char*    Xq1 = (signed char*)(ws + szA + 2 * szH);
    signed char*    Xq2 = (signed char*)(ws + szA + 2 * szH + szXq);
    float*          ub  = (float*)(ws + szA + 2 * szH + 2 * szXq);

    cvt_i8<<<dim3(2048), blk256, 0, stream>>>(supports, Aq, 8388608);
    pack_x1<<<dim3(128), blk256, 0, stream>>>(inputs, states, H1, Xq1);

    dhop<<<dim3(64), dim3(512), 0, stream>>>(Aq, Xq1, H1, dq1, dq2);

    gate_ru_k<<<dim3(128), blk256, 0, stream>>>(H1, W_ru, b_ru, inputs, states, H2, Xq2, ub);

    dhop<<<dim3(64), dim3(512), 0, stream>>>(Aq, Xq2, H2, dq1, dq2);

    gate_c_k<<<dim3(128), blk256, 0, stream>>>(H2, W_c, b_c, states, ub, out);
  } else {
    unsigned short* H1 = (unsigned short*)ws;
    unsigned short* H2 = (unsigned short*)(ws + szH);
    float*          ub = (float*)(ws + 2 * szH);
    pack_x1<<<dim3(128), blk256, 0, stream>>>(inputs, states, H1, nullptr);
    hop_slow<<<sgrid, blk256, 0, stream>>>(supports, H1, H1, 0, 0, 1, 3);
    hop_slow<<<sgrid, blk256, 0, stream>>>(supports, H1, H1, 1, 3, 2, 4);
    gate_ru_k<<<dim3(128), blk256, 0, stream>>>(H1, W_ru, b_ru, inputs, states, H2, nullptr, ub);
    hop_slow<<<sgrid, blk256, 0, stream>>>(supports, H2, H2, 0, 0, 1, 3);
    hop_slow<<<sgrid, blk256, 0, stream>>>(supports, H2, H2, 1, 3, 2, 4);
    gate_c_k<<<dim3(128), blk256, 0, stream>>>(H2, W_c, b_c, states, ub, out);
  }
}